// Round 1
// baseline (1025.637 us; speedup 1.0000x reference)
//
#include <hip/hip_runtime.h>

#define KC    64     // candidates per batch
#define DD    384    // embedding dim
#define HH    64     // hidden 1
#define H2    32     // hidden 2
#define NTOP  8
#define NPAIR 28

#define NEG_INF (-3.402823466e38f)

__constant__ int c_ii[NPAIR] = {0,0,0,0,0,0,0, 1,1,1,1,1,1, 2,2,2,2,2, 3,3,3,3, 4,4,4, 5,5, 6};
__constant__ int c_jj[NPAIR] = {1,2,3,4,5,6,7, 2,3,4,5,6,7, 3,4,5,6,7, 4,5,6,7, 5,6,7, 6,7, 7};

__device__ __forceinline__ float silu_f(float x) {
    return x / (1.0f + __expf(-x));
}

__launch_bounds__(256, 4)
__global__ void rpe_kernel(const float* __restrict__ M,
                           const float* __restrict__ y,
                           const float* __restrict__ ts,
                           const float* __restrict__ W1,
                           const float* __restrict__ b1,
                           const float* __restrict__ W2,
                           const float* __restrict__ b2,
                           const float* __restrict__ W3,
                           const float* __restrict__ b3,
                           float* __restrict__ out)
{
    const int b   = blockIdx.x;
    const int tid = threadIdx.x;

    __shared__ int   s_idx[NTOP];
    __shared__ float s_ytop[NTOP];
    __shared__ float s_t[NTOP];
    // union buffer: first holds gathered M rows (8*384 fp32 = 12 KB),
    // later (after a barrier) the 4 per-wave partial P tiles (4*1024 = 16 KB)
    __shared__ __align__(16) float s_buf[4 * NTOP * 128];
    __shared__ __align__(16) float s_P[NTOP * 128];   // 4 KB  [k][0:64]=A-part, [64:128]=B-part
    __shared__ __align__(16) float s_h1[NPAIR * HH];  // 7 KB
    __shared__ float s_pen[NPAIR];

    // ---------- Phase A: top-8 of y[b, :], jax.lax.top_k semantics ----------
    if (tid < 64) {
        float v = y[(size_t)b * KC + tid];
        #pragma unroll
        for (int r = 0; r < NTOP; ++r) {
            float bv = v; int bi = tid;
            #pragma unroll
            for (int off = 32; off >= 1; off >>= 1) {
                float ov = __shfl_xor(bv, off, 64);
                int   oi = __shfl_xor(bi, off, 64);
                // larger value wins; on exact tie, smaller index wins
                if (ov > bv || (ov == bv && oi < bi)) { bv = ov; bi = oi; }
            }
            if (tid == 0) { s_idx[r] = bi; s_ytop[r] = bv; }
            if (tid == bi) v = NEG_INF;
        }
        // same wave that wrote s_idx: ordered within wave, safe to read
        if (tid < NTOP) {
            s_t[tid] = ts[(size_t)b * KC + s_idx[tid]];
        }
    }
    __syncthreads();

    // ---------- Phase B: gather top-8 rows of M into LDS ----------
    float* s_m = s_buf;  // [8][384]
    for (int q = tid; q < NTOP * 96; q += 256) {           // 96 float4 per row
        int r = q / 96, c4 = q - r * 96;
        const float4 v4 = *(const float4*)(M + ((size_t)b * KC + s_idx[r]) * DD + c4 * 4);
        *(float4*)(s_m + r * DD + c4 * 4) = v4;
    }
    __syncthreads();

    // ---------- Phase C: P[k][n] (8 x 128), n<64: m_k @ W1a, n>=64: m_k @ W1b ----------
    {
        const int g  = tid >> 5;        // 8 half-wave groups, each owns 48 K-slice
        const int lg = tid & 31;
        const int n0 = lg * 4;
        const float* wp = (n0 < HH) ? (W1 + n0) : (W1 + DD * HH + (n0 - HH));
        float acc[NTOP][4];
        #pragma unroll
        for (int k = 0; k < NTOP; ++k) {
            acc[k][0] = 0.f; acc[k][1] = 0.f; acc[k][2] = 0.f; acc[k][3] = 0.f;
        }
        const int d0 = g * 48;
        #pragma unroll 4
        for (int dd = 0; dd < 48; ++dd) {
            const int d = d0 + dd;
            const float4 w = *(const float4*)(wp + (size_t)d * HH);
            #pragma unroll
            for (int k = 0; k < NTOP; ++k) {
                const float mv = s_m[k * DD + d];
                acc[k][0] = fmaf(mv, w.x, acc[k][0]);
                acc[k][1] = fmaf(mv, w.y, acc[k][1]);
                acc[k][2] = fmaf(mv, w.z, acc[k][2]);
                acc[k][3] = fmaf(mv, w.w, acc[k][3]);
            }
        }
        // fold the two half-waves of each wave (same (k,n0) mapping, different d-slices)
        #pragma unroll
        for (int k = 0; k < NTOP; ++k) {
            #pragma unroll
            for (int j = 0; j < 4; ++j)
                acc[k][j] += __shfl_xor(acc[k][j], 32, 64);
        }
        __syncthreads();   // everyone done reading s_m; reuse s_buf for partials
        const int w = tid >> 6;  // wave id 0..3
        if ((tid & 63) < 32) {
            #pragma unroll
            for (int k = 0; k < NTOP; ++k) {
                #pragma unroll
                for (int j = 0; j < 4; ++j)
                    s_buf[w * 1024 + k * 128 + n0 + j] = acc[k][j];
            }
        }
    }
    __syncthreads();
    for (int q = tid; q < NTOP * 128; q += 256) {
        s_P[q] = s_buf[q] + s_buf[1024 + q] + s_buf[2048 + q] + s_buf[3072 + q];
    }
    __syncthreads();

    // ---------- Phase D: 28 pairs ----------
    // h1[p][n] = silu(P_a[i][n] + P_b[j][n] + dt*W1[768][n] + yi*W1[769][n] + yj*W1[770][n] + b1[n])
    for (int q = tid; q < NPAIR * HH; q += 256) {
        const int p = q >> 6;
        const int n = q & 63;
        const int i = c_ii[p], j = c_jj[p];
        float x = s_P[i * 128 + n] + s_P[j * 128 + 64 + n]
                + (s_t[i] - s_t[j]) * W1[768 * HH + n]
                + s_ytop[i]         * W1[769 * HH + n]
                + s_ytop[j]         * W1[770 * HH + n]
                + b1[n];
        s_h1[q] = silu_f(x);
    }
    __syncthreads();

    // layer 2 (64->32) + silu + layer 3 (32->1): 8 threads per pair, 4 outputs each
    if (tid < NPAIR * 8) {
        const int p  = tid >> 3;
        const int s  = tid & 7;
        const int m0 = s * 4;
        float a0 = 0.f, a1 = 0.f, a2 = 0.f, a3 = 0.f;
        #pragma unroll 8
        for (int d2 = 0; d2 < HH; ++d2) {
            const float hv = s_h1[p * HH + d2];
            const float4 w2 = *(const float4*)(W2 + d2 * H2 + m0);
            a0 = fmaf(hv, w2.x, a0);
            a1 = fmaf(hv, w2.y, a1);
            a2 = fmaf(hv, w2.z, a2);
            a3 = fmaf(hv, w2.w, a3);
        }
        float pe = silu_f(a0 + b2[m0 + 0]) * W3[m0 + 0]
                 + silu_f(a1 + b2[m0 + 1]) * W3[m0 + 1]
                 + silu_f(a2 + b2[m0 + 2]) * W3[m0 + 2]
                 + silu_f(a3 + b2[m0 + 3]) * W3[m0 + 3];
        #pragma unroll
        for (int off = 4; off >= 1; off >>= 1)
            pe += __shfl_down(pe, off, 8);
        if (s == 0) {
            const int i = c_ii[p], j = c_jj[p];
            s_pen[p] = (pe + b3[0]) * (s_ytop[i] * s_ytop[j]);
        }
    }
    __syncthreads();

    if (tid == 0) {
        float sum = 0.f;
        for (int p = 0; p < NPAIR; ++p) sum += s_pen[p];
        out[b] = sum;
    }
}

extern "C" void kernel_launch(void* const* d_in, const int* in_sizes, int n_in,
                              void* d_out, int out_size, void* d_ws, size_t ws_size,
                              hipStream_t stream) {
    const float* M  = (const float*)d_in[0];
    const float* y  = (const float*)d_in[1];
    const float* ts = (const float*)d_in[2];
    const float* W1 = (const float*)d_in[3];
    const float* b1 = (const float*)d_in[4];
    const float* W2 = (const float*)d_in[5];
    const float* b2 = (const float*)d_in[6];
    const float* W3 = (const float*)d_in[7];
    const float* b3 = (const float*)d_in[8];
    float* out = (float*)d_out;

    const int B = in_sizes[1] / KC;   // 8192
    rpe_kernel<<<dim3(B), dim3(256), 0, stream>>>(M, y, ts, W1, b1, W2, b2, W3, b3, out);
}

// Round 2
// 939.589 us; speedup vs baseline: 1.0916x; 1.0916x over previous
//
#include <hip/hip_runtime.h>

#define KC    64     // candidates per batch
#define DD    384    // embedding dim
#define HH    64     // hidden 1
#define H2    32     // hidden 2
#define NTOP  8
#define NPAIR 28
#define NKB   12     // K blocks of 32 (384/32)

#define NEG_INF (-3.402823466e38f)

typedef __attribute__((ext_vector_type(8))) short short8;
typedef __attribute__((ext_vector_type(4))) float floatx4;

__constant__ int c_ii[NPAIR] = {0,0,0,0,0,0,0, 1,1,1,1,1,1, 2,2,2,2,2, 3,3,3,3, 4,4,4, 5,5, 6};
__constant__ int c_jj[NPAIR] = {1,2,3,4,5,6,7, 2,3,4,5,6,7, 3,4,5,6,7, 4,5,6,7, 5,6,7, 6,7, 7};

__device__ __forceinline__ float silu_f(float x) {
    return x / (1.0f + __expf(-x));
}

__device__ __forceinline__ unsigned short f2bf(float f) {   // RNE fp32->bf16
    unsigned int u = __float_as_uint(f);
    u += 0x7FFFu + ((u >> 16) & 1u);
    return (unsigned short)(u >> 16);
}

// ---- prep: W1[0:768][0:64] -> bf16 B-fragments for mfma_f32_16x16x32_bf16 ----
// frag slot (t, kb, lane, j) = B[k = kb*32 + (lane>>4)*8 + j][n = t*16 + (lane&15)]
// where B[k][n] = (n<64) ? W1[k][n] : W1[384+k][n-64];  t in 0..7, kb in 0..11
__global__ void prep_w1(const float* __restrict__ W1, unsigned short* __restrict__ wf) {
    const int blk  = blockIdx.x;        // 96 blocks
    const int t    = blk / NKB;
    const int kb   = blk - t * NKB;
    const int lane = threadIdx.x;       // 64
    const int quad = lane >> 4;
    const int col  = lane & 15;
    const int n    = t * 16 + col;
    const int base_k = kb * 32 + quad * 8;
    const int row_off = (n < HH) ? 0 : 384;
    const int c       = (n < HH) ? n : n - HH;
    unsigned short us[8];
    #pragma unroll
    for (int j = 0; j < 8; ++j) {
        us[j] = f2bf(W1[(size_t)(row_off + base_k + j) * HH + c]);
    }
    short8 v;
    #pragma unroll
    for (int j = 0; j < 8; ++j) v[j] = (short)us[j];
    *(short8*)(wf + ((size_t)(t * NKB + kb) * 64 + lane) * 8) = v;
}

union ABUnion {
    short a[NKB * 64 * 8];        // 12 KB: A fragments (bf16 as short)
    float h1[2 * NPAIR * HH];     // 14 KB: h1 for both batches (phase D)
};

__launch_bounds__(256, 4)
__global__ void rpe_kernel(const float* __restrict__ M,
                           const float* __restrict__ y,
                           const float* __restrict__ ts,
                           const float* __restrict__ W1,
                           const float* __restrict__ b1,
                           const float* __restrict__ W2,
                           const float* __restrict__ b2,
                           const float* __restrict__ W3,
                           const float* __restrict__ b3,
                           const unsigned short* __restrict__ wf,
                           float* __restrict__ out)
{
    const int blk = blockIdx.x;   // handles batches 2*blk, 2*blk+1
    const int tid = threadIdx.x;

    __shared__ __align__(16) ABUnion s_u;
    __shared__ __align__(16) float s_P[16 * 128];     // 8 KB  P[m][n]
    __shared__ __align__(16) float s_W2[HH * H2];     // 8 KB
    __shared__ float s_misc[324]; // [0:64] w_dt, [64:128] w_yi, [128:192] w_yj,
                                  // [192:256] b1, [256:288] b2, [288:320] W3, [320] b3
    __shared__ int   s_idx[2][NTOP];
    __shared__ float s_ytop[2][NTOP];
    __shared__ float s_t[2][NTOP];
    __shared__ float s_pen[2 * NPAIR];

    // ---------- Phase A (waves 0,1): top-8 per batch; waves 2,3: stage W2/misc ----------
    if (tid < 128) {
        const int w    = tid >> 6;            // batch-half 0/1
        const int lane = tid & 63;
        const size_t bb = (size_t)blk * 2 + w;
        float v = y[bb * KC + lane];
        float myv = 0.f; int myi = 0;
        #pragma unroll
        for (int r = 0; r < NTOP; ++r) {
            float bv = v; int bi = lane;
            #pragma unroll
            for (int off = 32; off >= 1; off >>= 1) {
                float ov = __shfl_xor(bv, off, 64);
                int   oi = __shfl_xor(bi, off, 64);
                if (ov > bv || (ov == bv && oi < bi)) { bv = ov; bi = oi; }
            }
            if (lane == r) { myv = bv; myi = bi; }
            if (lane == bi) v = NEG_INF;
        }
        if (lane < NTOP) {
            s_idx[w][lane]  = myi;
            s_ytop[w][lane] = myv;
            s_t[w][lane]    = ts[bb * KC + myi];
        }
    } else {
        const int lt = tid - 128;             // 0..127
        for (int q = lt; q < (HH * H2) / 4; q += 128)
            ((float4*)s_W2)[q] = ((const float4*)W2)[q];
        if (lt < 64) {
            s_misc[lt]       = W1[(size_t)768 * HH + lt];
            s_misc[64 + lt]  = W1[(size_t)769 * HH + lt];
            s_misc[128 + lt] = W1[(size_t)770 * HH + lt];
            s_misc[192 + lt] = b1[lt];
        } else if (lt < 96) {
            const int z = lt - 64;
            s_misc[256 + z] = b2[z];
            s_misc[288 + z] = W3[z];
        } else if (lt == 96) {
            s_misc[320] = b3[0];
        }
    }
    __syncthreads();

    // ---------- Phase B: gather 16 M rows -> bf16 A-fragments in LDS ----------
    // slot (kb, flane, j) = A[m = flane&15][k = kb*32 + (flane>>4)*8 + j]
    for (int q = tid; q < 16 * 48; q += 256) {
        const int m  = q / 48;
        const int k8 = q - m * 48;
        const int row = s_idx[m >> 3][m & 7];
        const size_t bb = (size_t)blk * 2 + (m >> 3);
        const float* src = M + ((bb * KC + row) * DD) + k8 * 8;
        const float4 f0 = *(const float4*)(src);
        const float4 f1 = *(const float4*)(src + 4);
        short8 v;
        v[0] = (short)f2bf(f0.x); v[1] = (short)f2bf(f0.y);
        v[2] = (short)f2bf(f0.z); v[3] = (short)f2bf(f0.w);
        v[4] = (short)f2bf(f1.x); v[5] = (short)f2bf(f1.y);
        v[6] = (short)f2bf(f1.z); v[7] = (short)f2bf(f1.w);
        const int kb = k8 >> 2, quad = k8 & 3;
        *(short8*)(&s_u.a[((kb * 64) + quad * 16 + m) * 8]) = v;
    }
    __syncthreads();

    // ---------- Phase C: P(16x128) = A(16x384) @ B(384x128) via MFMA ----------
    {
        const int w    = tid >> 6;    // wave 0..3
        const int lane = tid & 63;
        const int t0 = 2 * w, t1 = 2 * w + 1;
        floatx4 acc0 = {0.f, 0.f, 0.f, 0.f};
        floatx4 acc1 = {0.f, 0.f, 0.f, 0.f};
        const short8* bf0 = (const short8*)(wf + ((size_t)t0 * NKB * 64) * 8);
        const short8* bf1 = (const short8*)(wf + ((size_t)t1 * NKB * 64) * 8);
        #pragma unroll 4
        for (int kb = 0; kb < NKB; ++kb) {
            const short8 a  = *(const short8*)(&s_u.a[(kb * 64 + lane) * 8]);
            const short8 bx = bf0[kb * 64 + lane];
            const short8 by = bf1[kb * 64 + lane];
            acc0 = __builtin_amdgcn_mfma_f32_16x16x32_bf16(a, bx, acc0, 0, 0, 0);
            acc1 = __builtin_amdgcn_mfma_f32_16x16x32_bf16(a, by, acc1, 0, 0, 0);
        }
        // D layout: col = lane&15, row = (lane>>4)*4 + reg
        const int col = lane & 15, quad = lane >> 4;
        #pragma unroll
        for (int r = 0; r < 4; ++r) {
            const int row = quad * 4 + r;
            s_P[row * 128 + t0 * 16 + col] = acc0[r];
            s_P[row * 128 + t1 * 16 + col] = acc1[r];
        }
    }
    __syncthreads();

    // ---------- Phase D1: h1 for 28 pairs x 2 batches ----------
    {
        const int hb = tid >> 7;        // batch-half
        const int lt = tid & 127;
        for (int q = lt; q < NPAIR * HH; q += 128) {
            const int p = q >> 6;
            const int n = q & 63;
            const int i = c_ii[p], j = c_jj[p];
            float x = s_P[(hb * 8 + i) * 128 + n]
                    + s_P[(hb * 8 + j) * 128 + 64 + n]
                    + (s_t[hb][i] - s_t[hb][j]) * s_misc[n]
                    + s_ytop[hb][i]             * s_misc[64 + n]
                    + s_ytop[hb][j]             * s_misc[128 + n]
                    + s_misc[192 + n];
            s_u.h1[(hb * NPAIR + p) * HH + n] = silu_f(x);
        }
    }
    __syncthreads();

    // ---------- Phase D2: layer2 (64->32) + silu + layer3 (32->1) ----------
    {
        const int hb = tid >> 7;
        const int lt = tid & 127;
        if (lt < NPAIR * 4) {
            const int p  = lt >> 2;
            const int s  = lt & 3;
            const int m0 = s * 8;
            float acc[8];
            #pragma unroll
            for (int c = 0; c < 8; ++c) acc[c] = 0.f;
            const float* h1p = &s_u.h1[(hb * NPAIR + p) * HH];
            #pragma unroll 8
            for (int d2 = 0; d2 < HH; ++d2) {
                const float hv = h1p[d2];
                const float4 wlo = *(const float4*)(&s_W2[d2 * H2 + m0]);
                const float4 whi = *(const float4*)(&s_W2[d2 * H2 + m0 + 4]);
                acc[0] = fmaf(hv, wlo.x, acc[0]); acc[1] = fmaf(hv, wlo.y, acc[1]);
                acc[2] = fmaf(hv, wlo.z, acc[2]); acc[3] = fmaf(hv, wlo.w, acc[3]);
                acc[4] = fmaf(hv, whi.x, acc[4]); acc[5] = fmaf(hv, whi.y, acc[5]);
                acc[6] = fmaf(hv, whi.z, acc[6]); acc[7] = fmaf(hv, whi.w, acc[7]);
            }
            float pe = 0.f;
            #pragma unroll
            for (int c = 0; c < 8; ++c)
                pe += silu_f(acc[c] + s_misc[256 + m0 + c]) * s_misc[288 + m0 + c];
            pe += __shfl_down(pe, 2, 4);
            pe += __shfl_down(pe, 1, 4);
            if (s == 0) {
                const int i = c_ii[p], j = c_jj[p];
                s_pen[hb * NPAIR + p] = (pe + s_misc[320]) * (s_ytop[hb][i] * s_ytop[hb][j]);
            }
        }
    }
    __syncthreads();

    if (tid == 0) {
        float sum = 0.f;
        #pragma unroll
        for (int p = 0; p < NPAIR; ++p) sum += s_pen[p];
        out[(size_t)blk * 2] = sum;
    }
    if (tid == 128) {
        float sum = 0.f;
        #pragma unroll
        for (int p = 0; p < NPAIR; ++p) sum += s_pen[NPAIR + p];
        out[(size_t)blk * 2 + 1] = sum;
    }
}

extern "C" void kernel_launch(void* const* d_in, const int* in_sizes, int n_in,
                              void* d_out, int out_size, void* d_ws, size_t ws_size,
                              hipStream_t stream) {
    const float* M  = (const float*)d_in[0];
    const float* y  = (const float*)d_in[1];
    const float* ts = (const float*)d_in[2];
    const float* W1 = (const float*)d_in[3];
    const float* b1 = (const float*)d_in[4];
    const float* W2 = (const float*)d_in[5];
    const float* b2 = (const float*)d_in[6];
    const float* W3 = (const float*)d_in[7];
    const float* b3 = (const float*)d_in[8];
    float* out = (float*)d_out;
    unsigned short* wf = (unsigned short*)d_ws;   // 8*12*64*8 ushorts = 192 KB

    const int B = in_sizes[1] / KC;   // 8192

    prep_w1<<<dim3(8 * NKB), dim3(64), 0, stream>>>(W1, wf);
    rpe_kernel<<<dim3(B / 2), dim3(256), 0, stream>>>(M, y, ts, W1, b1, W2, b2, W3, b3, wf, out);
}